// Round 2
// baseline (299.794 us; speedup 1.0000x reference)
//
#include <hip/hip_runtime.h>

typedef _Float16 half_t;
typedef _Float16 half8 __attribute__((ext_vector_type(8)));
typedef float f32x4 __attribute__((ext_vector_type(4)));

#define MFMA16(a, b, c) __builtin_amdgcn_mfma_f32_16x16x32_f16((a), (b), (c), 0, 0, 0)

static constexpr int kM  = 512;
static constexpr int kD  = 64;
static constexpr int kKL = 2560;
static constexpr int kL  = 2048;
// ws layout (halves): q_scaled | K f16 | V^T f16 [bh][d][k] | peT f16 [l][d]
static constexpr int WS_QS  = 0;                    // 1,048,576
static constexpr int WS_KB  = 1048576;              // 5,242,880
static constexpr int WS_VT  = WS_KB + 5242880;      // 5,242,880
static constexpr int WS_PET = WS_VT + 5242880;      // 131,072
// total 11,665,408 halves = 23,330,816 B

// ---------- K1: q (pre-scaled) + k  f32 -> f16, 8 elems/thread ----------
__global__ __launch_bounds__(256) void cvt_kernel(const float* __restrict__ q,
    const float* __restrict__ k, half_t* __restrict__ ws) {
  const int i = blockIdx.x * 256 + threadIdx.x;   // 786,432 threads total
  const float QS = 0.125f * 1.4426950408889634f;  // 1/sqrt(64) * log2(e)
  const float* src; half_t* dst; float sc;
  if (i < 131072) { src = q + (size_t)i * 8; dst = ws + WS_QS + (size_t)i * 8; sc = QS; }
  else { const int j = i - 131072; src = k + (size_t)j * 8; dst = ws + WS_KB + (size_t)j * 8; sc = 1.0f; }
  const float4 a = ((const float4*)src)[0];
  const float4 b = ((const float4*)src)[1];
  half_t t[8];
  t[0] = (half_t)(a.x * sc); t[1] = (half_t)(a.y * sc);
  t[2] = (half_t)(a.z * sc); t[3] = (half_t)(a.w * sc);
  t[4] = (half_t)(b.x * sc); t[5] = (half_t)(b.y * sc);
  t[6] = (half_t)(b.z * sc); t[7] = (half_t)(b.w * sc);
  *(int4*)dst = *(int4*)t;
}

// ---------- K2: 64x64 tile transpose+convert: V -> Vt[bh][d][k], pe -> peT[l][d] ----------
__global__ __launch_bounds__(256) void trans_kernel(const float* __restrict__ v,
    const float* __restrict__ pe, half_t* __restrict__ ws) {
  __shared__ float ls[64 * 72];
  const int b = blockIdx.x, t = threadIdx.x;
  const float* src; int sstride; half_t* dst; int dstride;
  if (b < 1280) {                       // V: 32 bh x 40 key-tiles
    const int bh = b / 40, kt = b % 40;
    src = v + (size_t)(bh * 2560 + kt * 64) * 64; sstride = 64;      // rows = keys
    dst = ws + WS_VT + (size_t)bh * 163840 + kt * 64; dstride = 2560; // rows = dims
  } else {                              // pe: [64][2048] -> peT [2048][64], 32 l-tiles
    const int b2 = b - 1280;
    src = pe + (size_t)b2 * 64; sstride = 2048;                      // rows = dims
    dst = ws + WS_PET + (size_t)b2 * 64 * 64; dstride = 64;          // rows = l
  }
  const int rr = t >> 4, cq = (t & 15) * 4;
#pragma unroll
  for (int p = 0; p < 4; ++p) {
    const float4 x = *(const float4*)(src + (size_t)(p * 16 + rr) * sstride + cq);
    *(float4*)(ls + (p * 16 + rr) * 72 + cq) = x;
  }
  __syncthreads();
  const int oc = t >> 2, ch = t & 3;    // output row oc (= tile col), 16-elem chunk ch
  half_t tmp[16];
#pragma unroll
  for (int i2 = 0; i2 < 16; ++i2) tmp[i2] = (half_t)ls[(ch * 16 + i2) * 72 + oc];
  half_t* o = dst + (size_t)oc * dstride + ch * 16;
  ((int4*)o)[0] = ((int4*)tmp)[0];
  ((int4*)o)[1] = ((int4*)tmp)[1];
}

// ---------- K3: fused banded attention ----------
// grid = 1024 (bh x 16-row q-tile, XCD-swizzled), block = 512 (8 waves).
// Each wave owns ~1/8 of the 65 32-key tiles; 8-way merge in epilogue.
// K, V^T, peT B-frags load DIRECTLY from global (L2-resident per XCD).
// No online max: weight = pm/(sum pm + 1e-8 sum p) is scale-invariant, s bounded.
// Per-wave LDS 4608 B: peS[16][52] f16 | Pb[16][40] f16 ; epilogue Ow[16][68] f32 overlays.
__global__ __launch_bounds__(512, 8) void attn_kernel(
    const half_t* __restrict__ ws, const float* __restrict__ cvp,
    float* __restrict__ out) {

  __shared__ __align__(16) char smem[8 * 4608 + 1024];

  const int tid  = threadIdx.x;
  const int lane = tid & 63;
  const int w    = tid >> 6;
  const int c    = lane & 15;
  const int qd   = lane >> 4;

  const int id = blockIdx.x;
  const int bh = ((id & 7) << 2) | (id >> 8);   // XCD-aware: 4 bh per XCD
  const int mt = (id >> 3) & 31;
  const int m0 = mt << 4;

  const float cvl = cvp[bh & 7] * 2048.0f - 2047.0f;  // mask = clamp((l+cvl)/64+1, 0, 1)

  const half_t* kb   = ws + WS_KB + (size_t)bh * (kKL * kD);
  const half_t* vt   = ws + WS_VT + (size_t)bh * (kKL * kD);
  const half_t* pet  = ws + WS_PET;
  const half_t* qrow = ws + WS_QS + (size_t)(bh * kM + m0 + c) * kD;
  const half8 aq0 = *(const half8*)(qrow + qd * 8);
  const half8 aq1 = *(const half8*)(qrow + 32 + qd * 8);

  half_t* peS = (half_t*)(smem + w * 4608);           // [16][52]
  half_t* Pb  = (half_t*)(smem + w * 4608 + 1664);    // [16][40]

  float zal[4] = {0, 0, 0, 0}, zm[4] = {0, 0, 0, 0};
  f32x4 o0 = {0,0,0,0}, o1 = {0,0,0,0}, o2 = {0,0,0,0}, o3 = {0,0,0,0};

  const int t0 = (w * 65) >> 3;
  const int t1 = ((w + 1) * 65) >> 3;

  // PE bias window A for first tile (l = t0*32-16 + c); windows shift by 32/iter,
  // window C of tile t == window A of tile t+1 (carried in paccA).
  f32x4 paccA;
  {
    int l = t0 * 32 - 16 + c;
    l = (l < 0) ? 0 : (l > kL - 1 ? kL - 1 : l);
    const half8 b0 = *(const half8*)(pet + (size_t)l * kD + qd * 8);
    const half8 b1 = *(const half8*)(pet + (size_t)l * kD + 32 + qd * 8);
    f32x4 acc = {0,0,0,0};
    acc   = MFMA16(aq0, b0, acc);
    paccA = MFMA16(aq1, b1, acc);
  }

  for (int t = t0; t < t1; ++t) {
    const int rel0 = t * 32;
    const int n0   = m0 + rel0;

    // ---- K B-frags from global ----
    int kr0 = n0 + c;      if (kr0 > kKL - 1) kr0 = kKL - 1;
    int kr1 = n0 + 16 + c; if (kr1 > kKL - 1) kr1 = kKL - 1;
    const half8 bk00 = *(const half8*)(kb + (size_t)kr0 * kD + qd * 8);
    const half8 bk01 = *(const half8*)(kb + (size_t)kr0 * kD + 32 + qd * 8);
    const half8 bk10 = *(const half8*)(kb + (size_t)kr1 * kD + qd * 8);
    const half8 bk11 = *(const half8*)(kb + (size_t)kr1 * kD + 32 + qd * 8);

    // ---- PE windows B (l=rel0+c) and C (l=rel0+16+c) ----
    f32x4 paccB, paccC;
    {
      int lB = rel0 + c;      if (lB > kL - 1) lB = kL - 1;
      int lC = rel0 + 16 + c; if (lC > kL - 1) lC = kL - 1;
      const half8 pb0 = *(const half8*)(pet + (size_t)lB * kD + qd * 8);
      const half8 pb1 = *(const half8*)(pet + (size_t)lB * kD + 32 + qd * 8);
      const half8 pc0 = *(const half8*)(pet + (size_t)lC * kD + qd * 8);
      const half8 pc1 = *(const half8*)(pet + (size_t)lC * kD + 32 + qd * 8);
      f32x4 a1 = {0,0,0,0}, a2 = {0,0,0,0};
      a1    = MFMA16(aq0, pb0, a1);
      paccB = MFMA16(aq1, pb1, a1);
      a2    = MFMA16(aq0, pc0, a2);
      paccC = MFMA16(aq1, pc1, a2);
    }

    // stage bias tiles to LDS (diagonal realignment needs cross-lane)
#pragma unroll
    for (int reg = 0; reg < 4; ++reg) {
      const int r = qd * 4 + reg;
      peS[r * 52 + c]      = (half_t)paccA[reg];
      peS[r * 52 + 16 + c] = (half_t)paccB[reg];
      peS[r * 52 + 32 + c] = (half_t)paccC[reg];
    }
    paccA = paccC;

    // ---- S = Q.K^T ----
    f32x4 s0acc = {0,0,0,0}, s1acc = {0,0,0,0};
    s0acc = MFMA16(aq0, bk00, s0acc); s0acc = MFMA16(aq1, bk01, s0acc);
    s1acc = MFMA16(aq0, bk10, s1acc); s1acc = MFMA16(aq1, bk11, s1acc);

    // ---- softmax (fixed C=0, exp2 domain) + ramp mask, P -> LDS ----
#pragma unroll
    for (int reg = 0; reg < 4; ++reg) {
      const int r  = qd * 4 + reg;
      const int l0 = rel0 + c - r;
      const int l1 = l0 + 16;
      const float b0 = (float)peS[r * 52 + (c - r + 16)];
      const float b1 = (float)peS[r * 52 + (c - r + 32)];
      const float e0 = (l0 >= 0 && l0 < kL) ? (s0acc[reg] + b0) : -1e38f;
      const float e1 = (l1 >= 0 && l1 < kL) ? (s1acc[reg] + b1) : -1e38f;
      const float p0 = __builtin_amdgcn_exp2f(e0);
      const float p1 = __builtin_amdgcn_exp2f(e1);
      const float mk0 = fminf(fmaxf(((float)l0 + cvl) * 0.015625f + 1.0f, 0.0f), 1.0f);
      const float mk1 = fminf(fmaxf(((float)l1 + cvl) * 0.015625f + 1.0f, 0.0f), 1.0f);
      const float pm0 = p0 * mk0, pm1 = p1 * mk1;
      zal[reg] += p0 + p1;
      zm[reg]  += pm0 + pm1;
      Pb[r * 40 + c]      = (half_t)pm0;
      Pb[r * 40 + 16 + c] = (half_t)pm1;
    }

    // ---- V B-frags from global (pre-transposed), loaded late to cap VGPR ----
    int nv = n0 + qd * 8; if (nv > kKL - 8) nv = kKL - 8;
    const half8 bv0 = *(const half8*)(vt + (size_t)(c)      * kKL + nv);
    const half8 bv1 = *(const half8*)(vt + (size_t)(16 + c) * kKL + nv);
    const half8 bv2 = *(const half8*)(vt + (size_t)(32 + c) * kKL + nv);
    const half8 bv3 = *(const half8*)(vt + (size_t)(48 + c) * kKL + nv);

    // ---- PV ----
    const half8 ap = *(const half8*)(Pb + c * 40 + qd * 8);
    o0 = MFMA16(ap, bv0, o0);
    o1 = MFMA16(ap, bv1, o1);
    o2 = MFMA16(ap, bv2, o2);
    o3 = MFMA16(ap, bv3, o3);
  }

  // ---- per-row sums across the 16 c-lanes ----
#pragma unroll
  for (int reg = 0; reg < 4; ++reg) {
    float a = zal[reg], m = zm[reg];
    a += __shfl_xor(a, 1); a += __shfl_xor(a, 2); a += __shfl_xor(a, 4); a += __shfl_xor(a, 8);
    m += __shfl_xor(m, 1); m += __shfl_xor(m, 2); m += __shfl_xor(m, 4); m += __shfl_xor(m, 8);
    zal[reg] = a; zm[reg] = m;
  }
  float* mrgA = (float*)(smem + 8 * 4608);   // [8][16]
  float* mrgM = mrgA + 128;
  if (c == 0) {
#pragma unroll
    for (int reg = 0; reg < 4; ++reg) {
      const int r = qd * 4 + reg;
      mrgA[w * 16 + r] = zal[reg];
      mrgM[w * 16 + r] = zm[reg];
    }
  }
  float* Ow = (float*)(smem + w * 4608);     // [16][68] f32 overlays peS/Pb
#pragma unroll
  for (int reg = 0; reg < 4; ++reg) {
    const int r = qd * 4 + reg;
    Ow[r * 68 + c]      = o0[reg];
    Ow[r * 68 + 16 + c] = o1[reg];
    Ow[r * 68 + 32 + c] = o2[reg];
    Ow[r * 68 + 48 + c] = o3[reg];
  }
  __syncthreads();

  // ---- 8-way merge + final normalize (exact reference semantics) ----
  const int dd = tid & 63;
  const int rb = tid >> 6;
#pragma unroll
  for (int rr = 0; rr < 2; ++rr) {
    const int r = rb * 2 + rr;
    float za = 0.0f, zmm = 0.0f, ov = 0.0f;
#pragma unroll
    for (int ww = 0; ww < 8; ++ww) {
      za  += mrgA[ww * 16 + r];
      zmm += mrgM[ww * 16 + r];
      ov  += ((float*)(smem + ww * 4608))[r * 68 + dd];
    }
    out[((size_t)bh * kM + m0 + r) * kD + dd] = ov / (zmm + 1e-8f * za);
  }
}

extern "C" void kernel_launch(void* const* d_in, const int* in_sizes, int n_in,
                              void* d_out, int out_size, void* d_ws, size_t ws_size,
                              hipStream_t stream) {
  (void)in_sizes; (void)n_in; (void)out_size; (void)ws_size;
  const float* q  = (const float*)d_in[0];
  const float* k  = (const float*)d_in[1];
  const float* v  = (const float*)d_in[2];
  const float* pe = (const float*)d_in[3];
  const float* cv = (const float*)d_in[4];
  half_t* ws = (half_t*)d_ws;   // needs 23,330,816 bytes
  float* out = (float*)d_out;

  cvt_kernel<<<3072, 256, 0, stream>>>(q, k, ws);          // q + k convert
  trans_kernel<<<1312, 256, 0, stream>>>(v, pe, ws);       // V^T + peT convert
  attn_kernel<<<1024, 512, 0, stream>>>(ws, cv, out);
}

// Round 3
// 184.432 us; speedup vs baseline: 1.6255x; 1.6255x over previous
//
#include <hip/hip_runtime.h>

typedef _Float16 half_t;
typedef _Float16 half8 __attribute__((ext_vector_type(8)));
typedef float f32x4 __attribute__((ext_vector_type(4)));

#define MFMA16(a, b, c) __builtin_amdgcn_mfma_f32_16x16x32_f16((a), (b), (c), 0, 0, 0)

static constexpr int kM  = 512;
static constexpr int kD  = 64;
static constexpr int kKL = 2560;
static constexpr int kL  = 2048;
// ws layout (halves): q_scaled | K f16 | V^T f16 [bh][d][k] | peT f16 [l][d]
static constexpr int WS_QS  = 0;                    // 1,048,576
static constexpr int WS_KB  = 1048576;              // 5,242,880
static constexpr int WS_VT  = WS_KB + 5242880;      // 5,242,880
static constexpr int WS_PET = WS_VT + 5242880;      // 131,072
// total 11,665,408 halves = 23,330,816 B

// ---------- K1 (fused): q/k convert + V,pe transpose-convert ----------
// blocks [0,3072): q+k elementwise f32->f16 (q pre-scaled), 8 elems/thread
// blocks [3072,4352): V 64x64 tile transpose -> Vt[bh][d][k]
// blocks [4352,4384): pe 64x64 tile transpose -> peT[l][d]
__global__ __launch_bounds__(256) void prep_kernel(const float* __restrict__ q,
    const float* __restrict__ k, const float* __restrict__ v,
    const float* __restrict__ pe, half_t* __restrict__ ws) {
  __shared__ float ls[64 * 72];
  const int b = blockIdx.x, t = threadIdx.x;
  if (b < 3072) {
    const int i = b * 256 + t;
    const float QS = 0.125f * 1.4426950408889634f;  // 1/sqrt(64) * log2(e)
    const float* src; half_t* dst; float sc;
    if (i < 131072) { src = q + (size_t)i * 8; dst = ws + WS_QS + (size_t)i * 8; sc = QS; }
    else { const int j = i - 131072; src = k + (size_t)j * 8; dst = ws + WS_KB + (size_t)j * 8; sc = 1.0f; }
    const float4 a = ((const float4*)src)[0];
    const float4 bb = ((const float4*)src)[1];
    half_t tt[8];
    tt[0] = (half_t)(a.x * sc);  tt[1] = (half_t)(a.y * sc);
    tt[2] = (half_t)(a.z * sc);  tt[3] = (half_t)(a.w * sc);
    tt[4] = (half_t)(bb.x * sc); tt[5] = (half_t)(bb.y * sc);
    tt[6] = (half_t)(bb.z * sc); tt[7] = (half_t)(bb.w * sc);
    *(int4*)dst = *(int4*)tt;
    return;
  }
  const float* src; int sstride; half_t* dst; int dstride;
  if (b < 4352) {                       // V: 32 bh x 40 key-tiles
    const int b2 = b - 3072;
    const int bh = b2 / 40, kt = b2 % 40;
    src = v + (size_t)(bh * 2560 + kt * 64) * 64; sstride = 64;       // rows = keys
    dst = ws + WS_VT + (size_t)bh * 163840 + kt * 64; dstride = 2560; // rows = dims
  } else {                              // pe: [64][2048] -> peT [2048][64], 32 l-tiles
    const int b3 = b - 4352;
    src = pe + (size_t)b3 * 64; sstride = 2048;                       // rows = dims
    dst = ws + WS_PET + (size_t)b3 * 64 * 64; dstride = 64;           // rows = l
  }
  const int rr = t >> 4, cq = (t & 15) * 4;
#pragma unroll
  for (int p = 0; p < 4; ++p) {
    const float4 x = *(const float4*)(src + (size_t)(p * 16 + rr) * sstride + cq);
    *(float4*)(ls + (p * 16 + rr) * 72 + cq) = x;
  }
  __syncthreads();
  const int oc = t >> 2, ch = t & 3;    // output row oc (= tile col), 16-elem chunk ch
  half_t tmp[16];
#pragma unroll
  for (int i2 = 0; i2 < 16; ++i2) tmp[i2] = (half_t)ls[(ch * 16 + i2) * 72 + oc];
  half_t* o = dst + (size_t)oc * dstride + ch * 16;
  ((int4*)o)[0] = ((int4*)tmp)[0];
  ((int4*)o)[1] = ((int4*)tmp)[1];
}

// ---------- K2: fused banded attention ----------
// grid = 1024 (bh x 16-row q-tile, XCD-swizzled), block = 512 (8 waves).
// Each wave owns ~1/8 of the 65 32-key tiles; 8-way merge in epilogue.
// K, V^T, peT B-frags load DIRECTLY from global (L2-resident per XCD).
// No online max: weight = pm/(sum pm + 1e-8 sum p) is scale-invariant, s bounded.
// launch_bounds(512,4): VGPR budget 128 — (512,8) forced 32 VGPRs + scratch
// spills (FETCH 536MB, 2x slowdown). 50% occupancy, no spills.
__global__ __launch_bounds__(512, 4) void attn_kernel(
    const half_t* __restrict__ ws, const float* __restrict__ cvp,
    float* __restrict__ out) {

  __shared__ __align__(16) char smem[8 * 4608 + 1024];

  const int tid  = threadIdx.x;
  const int lane = tid & 63;
  const int w    = tid >> 6;
  const int c    = lane & 15;
  const int qd   = lane >> 4;

  const int id = blockIdx.x;
  const int bh = ((id & 7) << 2) | (id >> 8);   // XCD-aware: 4 bh per XCD
  const int mt = (id >> 3) & 31;
  const int m0 = mt << 4;

  const float cvl = cvp[bh & 7] * 2048.0f - 2047.0f;  // mask = clamp((l+cvl)/64+1, 0, 1)

  const half_t* kb   = ws + WS_KB + (size_t)bh * (kKL * kD);
  const half_t* vt   = ws + WS_VT + (size_t)bh * (kKL * kD);
  const half_t* pet  = ws + WS_PET;
  const half_t* qrow = ws + WS_QS + (size_t)(bh * kM + m0 + c) * kD;
  const half8 aq0 = *(const half8*)(qrow + qd * 8);
  const half8 aq1 = *(const half8*)(qrow + 32 + qd * 8);

  half_t* peS = (half_t*)(smem + w * 4608);           // [16][52]
  half_t* Pb  = (half_t*)(smem + w * 4608 + 1664);    // [16][40]

  float zal[4] = {0, 0, 0, 0}, zm[4] = {0, 0, 0, 0};
  f32x4 o0 = {0,0,0,0}, o1 = {0,0,0,0}, o2 = {0,0,0,0}, o3 = {0,0,0,0};

  const int t0 = (w * 65) >> 3;
  const int t1 = ((w + 1) * 65) >> 3;

  // PE bias window A for first tile (l = t0*32-16 + c); windows shift by 32/iter,
  // window C of tile t == window A of tile t+1 (carried in paccA).
  f32x4 paccA;
  {
    int l = t0 * 32 - 16 + c;
    l = (l < 0) ? 0 : (l > kL - 1 ? kL - 1 : l);
    const half8 b0 = *(const half8*)(pet + (size_t)l * kD + qd * 8);
    const half8 b1 = *(const half8*)(pet + (size_t)l * kD + 32 + qd * 8);
    f32x4 acc = {0,0,0,0};
    acc   = MFMA16(aq0, b0, acc);
    paccA = MFMA16(aq1, b1, acc);
  }

  for (int t = t0; t < t1; ++t) {
    const int rel0 = t * 32;
    const int n0   = m0 + rel0;

    // ---- K B-frags from global ----
    int kr0 = n0 + c;      if (kr0 > kKL - 1) kr0 = kKL - 1;
    int kr1 = n0 + 16 + c; if (kr1 > kKL - 1) kr1 = kKL - 1;
    const half8 bk00 = *(const half8*)(kb + (size_t)kr0 * kD + qd * 8);
    const half8 bk01 = *(const half8*)(kb + (size_t)kr0 * kD + 32 + qd * 8);
    const half8 bk10 = *(const half8*)(kb + (size_t)kr1 * kD + qd * 8);
    const half8 bk11 = *(const half8*)(kb + (size_t)kr1 * kD + 32 + qd * 8);

    // ---- PE windows B (l=rel0+c) and C (l=rel0+16+c) ----
    f32x4 paccB, paccC;
    {
      int lB = rel0 + c;      if (lB > kL - 1) lB = kL - 1;
      int lC = rel0 + 16 + c; if (lC > kL - 1) lC = kL - 1;
      const half8 pb0 = *(const half8*)(pet + (size_t)lB * kD + qd * 8);
      const half8 pb1 = *(const half8*)(pet + (size_t)lB * kD + 32 + qd * 8);
      const half8 pc0 = *(const half8*)(pet + (size_t)lC * kD + qd * 8);
      const half8 pc1 = *(const half8*)(pet + (size_t)lC * kD + 32 + qd * 8);
      f32x4 a1 = {0,0,0,0}, a2 = {0,0,0,0};
      a1    = MFMA16(aq0, pb0, a1);
      paccB = MFMA16(aq1, pb1, a1);
      a2    = MFMA16(aq0, pc0, a2);
      paccC = MFMA16(aq1, pc1, a2);
    }

    // stage bias tiles to LDS (diagonal realignment needs cross-lane)
#pragma unroll
    for (int reg = 0; reg < 4; ++reg) {
      const int r = qd * 4 + reg;
      peS[r * 52 + c]      = (half_t)paccA[reg];
      peS[r * 52 + 16 + c] = (half_t)paccB[reg];
      peS[r * 52 + 32 + c] = (half_t)paccC[reg];
    }
    paccA = paccC;

    // ---- S = Q.K^T ----
    f32x4 s0acc = {0,0,0,0}, s1acc = {0,0,0,0};
    s0acc = MFMA16(aq0, bk00, s0acc); s0acc = MFMA16(aq1, bk01, s0acc);
    s1acc = MFMA16(aq0, bk10, s1acc); s1acc = MFMA16(aq1, bk11, s1acc);

    // ---- softmax (fixed C=0, exp2 domain) + ramp mask, P -> LDS ----
#pragma unroll
    for (int reg = 0; reg < 4; ++reg) {
      const int r  = qd * 4 + reg;
      const int l0 = rel0 + c - r;
      const int l1 = l0 + 16;
      const float b0 = (float)peS[r * 52 + (c - r + 16)];
      const float b1 = (float)peS[r * 52 + (c - r + 32)];
      const float e0 = (l0 >= 0 && l0 < kL) ? (s0acc[reg] + b0) : -1e38f;
      const float e1 = (l1 >= 0 && l1 < kL) ? (s1acc[reg] + b1) : -1e38f;
      const float p0 = __builtin_amdgcn_exp2f(e0);
      const float p1 = __builtin_amdgcn_exp2f(e1);
      const float mk0 = fminf(fmaxf(((float)l0 + cvl) * 0.015625f + 1.0f, 0.0f), 1.0f);
      const float mk1 = fminf(fmaxf(((float)l1 + cvl) * 0.015625f + 1.0f, 0.0f), 1.0f);
      const float pm0 = p0 * mk0, pm1 = p1 * mk1;
      zal[reg] += p0 + p1;
      zm[reg]  += pm0 + pm1;
      Pb[r * 40 + c]      = (half_t)pm0;
      Pb[r * 40 + 16 + c] = (half_t)pm1;
    }

    // ---- V B-frags from global (pre-transposed) ----
    int nv = n0 + qd * 8; if (nv > kKL - 8) nv = kKL - 8;
    const half8 bv0 = *(const half8*)(vt + (size_t)(c)      * kKL + nv);
    const half8 bv1 = *(const half8*)(vt + (size_t)(16 + c) * kKL + nv);
    const half8 bv2 = *(const half8*)(vt + (size_t)(32 + c) * kKL + nv);
    const half8 bv3 = *(const half8*)(vt + (size_t)(48 + c) * kKL + nv);

    // ---- PV ----
    const half8 ap = *(const half8*)(Pb + c * 40 + qd * 8);
    o0 = MFMA16(ap, bv0, o0);
    o1 = MFMA16(ap, bv1, o1);
    o2 = MFMA16(ap, bv2, o2);
    o3 = MFMA16(ap, bv3, o3);
  }

  // ---- per-row sums across the 16 c-lanes ----
#pragma unroll
  for (int reg = 0; reg < 4; ++reg) {
    float a = zal[reg], m = zm[reg];
    a += __shfl_xor(a, 1); a += __shfl_xor(a, 2); a += __shfl_xor(a, 4); a += __shfl_xor(a, 8);
    m += __shfl_xor(m, 1); m += __shfl_xor(m, 2); m += __shfl_xor(m, 4); m += __shfl_xor(m, 8);
    zal[reg] = a; zm[reg] = m;
  }
  float* mrgA = (float*)(smem + 8 * 4608);   // [8][16]
  float* mrgM = mrgA + 128;
  if (c == 0) {
#pragma unroll
    for (int reg = 0; reg < 4; ++reg) {
      const int r = qd * 4 + reg;
      mrgA[w * 16 + r] = zal[reg];
      mrgM[w * 16 + r] = zm[reg];
    }
  }
  float* Ow = (float*)(smem + w * 4608);     // [16][68] f32 overlays peS/Pb
#pragma unroll
  for (int reg = 0; reg < 4; ++reg) {
    const int r = qd * 4 + reg;
    Ow[r * 68 + c]      = o0[reg];
    Ow[r * 68 + 16 + c] = o1[reg];
    Ow[r * 68 + 32 + c] = o2[reg];
    Ow[r * 68 + 48 + c] = o3[reg];
  }
  __syncthreads();

  // ---- 8-way merge + final normalize (exact reference semantics) ----
  const int dd = tid & 63;
  const int rb = tid >> 6;
#pragma unroll
  for (int rr = 0; rr < 2; ++rr) {
    const int r = rb * 2 + rr;
    float za = 0.0f, zmm = 0.0f, ov = 0.0f;
#pragma unroll
    for (int ww = 0; ww < 8; ++ww) {
      za  += mrgA[ww * 16 + r];
      zmm += mrgM[ww * 16 + r];
      ov  += ((float*)(smem + ww * 4608))[r * 68 + dd];
    }
    out[((size_t)bh * kM + m0 + r) * kD + dd] = ov / (zmm + 1e-8f * za);
  }
}

extern "C" void kernel_launch(void* const* d_in, const int* in_sizes, int n_in,
                              void* d_out, int out_size, void* d_ws, size_t ws_size,
                              hipStream_t stream) {
  (void)in_sizes; (void)n_in; (void)out_size; (void)ws_size;
  const float* q  = (const float*)d_in[0];
  const float* k  = (const float*)d_in[1];
  const float* v  = (const float*)d_in[2];
  const float* pe = (const float*)d_in[3];
  const float* cv = (const float*)d_in[4];
  half_t* ws = (half_t*)d_ws;   // needs 23,330,816 bytes
  float* out = (float*)d_out;

  prep_kernel<<<4384, 256, 0, stream>>>(q, k, v, pe, ws);
  attn_kernel<<<1024, 512, 0, stream>>>(ws, cv, out);
}